// Round 8
// baseline (263.560 us; speedup 1.0000x reference)
//
#include <hip/hip_runtime.h>
#include <cstdint>
#include <cstddef>

typedef unsigned short u16;
typedef __attribute__((ext_vector_type(8))) short bf16x8;
typedef __attribute__((ext_vector_type(4))) float f32x4;
typedef __attribute__((ext_vector_type(8))) unsigned short u16x8;

#define T_TOK 8192
#define H_DIM 1024
#define F_DIM 4096
#define E_NUM 8
#define CAP (T_TOK / E_NUM)

template <int I> struct IC { static constexpr int v = I; };

__device__ __forceinline__ u16 f2bf(float f) {
  union { float f; uint32_t u; } v; v.f = f;
  uint32_t r = v.u + 0x7FFFu + ((v.u >> 16) & 1u);
  return (u16)(r >> 16);
}

__device__ __forceinline__ float gelu_tanh(float x) {
  float z2 = 1.5957691216057308f * (x + 0.044715f * x * x * x);
  float e = __expf(z2);
  return x * (1.0f - 1.0f / (e + 1.0f));
}

__device__ __forceinline__ void async_copy16(const void* gsrc, void* ldst) {
  __builtin_amdgcn_global_load_lds(
      (const __attribute__((address_space(1))) uint32_t*)gsrc,
      (__attribute__((address_space(3))) uint32_t*)ldst, 16, 0, 0);
}

__device__ __forceinline__ void wgbar() {
  asm volatile("" ::: "memory");
  __builtin_amdgcn_s_barrier();
  asm volatile("" ::: "memory");
}

template <int N> __device__ __forceinline__ void vm_wait() {
  static_assert(N == 0 || N == 3 || N == 6 || N == 8, "vm_wait: unsupported N");
  if constexpr (N == 0) asm volatile("s_waitcnt vmcnt(0)" ::: "memory");
  else if constexpr (N == 3) asm volatile("s_waitcnt vmcnt(3)" ::: "memory");
  else if constexpr (N == 6) asm volatile("s_waitcnt vmcnt(6)" ::: "memory");
  else if constexpr (N == 8) asm volatile("s_waitcnt vmcnt(8)" ::: "memory");
}

// ---- fp32 -> bf16 convert ----
__global__ __launch_bounds__(256) void k_convert(const float* __restrict__ src,
                                                 u16* __restrict__ dst, long n) {
  long i = ((long)blockIdx.x * 256 + threadIdx.x) * 8;
  long stride = (long)gridDim.x * 256 * 8;
  for (; i < n; i += stride) {
    const float4 a = *(const float4*)(src + i);
    const float4 b = *(const float4*)(src + i + 4);
    u16x8 o;
    o[0] = f2bf(a.x); o[1] = f2bf(a.y); o[2] = f2bf(a.z); o[3] = f2bf(a.w);
    o[4] = f2bf(b.x); o[5] = f2bf(b.y); o[6] = f2bf(b.z); o[7] = f2bf(b.w);
    *(u16x8*)(dst + i) = o;
  }
}

// ---- w2 [E][F][H] fp32 -> w2t [E][H][F] bf16 ----
__global__ __launch_bounds__(256) void k_transpose_w2(const float* __restrict__ w2,
                                                      u16* __restrict__ w2t) {
  __shared__ float tile[32][33];
  const int ntH = H_DIM / 32;
  const int ntF = F_DIM / 32;
  int bid = blockIdx.x;
  int e = bid / (ntF * ntH);
  int r = bid % (ntF * ntH);
  int f0 = (r / ntH) * 32;
  int h0 = (r % ntH) * 32;
  const float* src = w2 + (size_t)e * F_DIM * H_DIM;
  u16* dst = w2t + (size_t)e * H_DIM * F_DIM;
  int col = threadIdx.x & 31;
  int row8 = threadIdx.x >> 5;
#pragma unroll
  for (int i = 0; i < 4; i++) {
    int row = row8 + i * 8;
    tile[row][col] = src[(size_t)(f0 + row) * H_DIM + h0 + col];
  }
  __syncthreads();
#pragma unroll
  for (int i = 0; i < 4; i++) {
    int row = row8 + i * 8;
    dst[(size_t)(h0 + row) * F_DIM + f0 + col] = f2bf(tile[col][row]);
  }
}

// ==== m201-literal phase GEMM: C = A(256xK) * B^T (B=[N][K]) bf16 K-contig.
// 256xBN tile, BK=64 = 2 kh, 8 waves (WM x WN), 512 thr, 16x16x32 MFMA.
// Pieces: A[4]=[256][32] u16, B[4]=[BN][32]; piece slot = (t&1)*2+kh.
// Phase: [plain-load ds_reads for THIS phase][stage][barrier]
//        [setprio(1) 16xMFMA setprio(0) -- compiler inserts per-operand
//         counted lgkmcnt -> intra/inter-wave stagger][vmcnt][barrier].
// NO explicit lgkm waits / sched_barrier: ds_reads are compiler-visible, so
// true deps generate counted waits; waves drain LDS under other waves' MFMA.
// vmcnt FIFO (NPH4, stage q0:A(t+1,1) q1:B(t+1,1) q2:A(t+2,0) q3:B(t+2,0),
// waits <6> at q1/q3-end): q3(t-1)-end certifies A(t,1); q1(t)-end certifies
// B(t,1),A(t+1,0) -- each exactly one barrier before first read. NPH2
// (stage q0:AB(t+1,1) q1:AB(t+2,0), wait <3> every phase-end): q0-end
// certifies (t,1)... one barrier early. Tail t>=NT-3: vmcnt(0).
template <int BN, int WM, int WN, int NTN, int NT, bool GELU, int NPH>
__global__ __launch_bounds__(512, 2) void k_gemm(const u16* __restrict__ Ag,
                                                 const u16* __restrict__ Bg,
                                                 void* __restrict__ Cg) {
  constexpr int K = NT * 64;
  constexpr int WROWS = 256 / WM;
  constexpr int WCOLS = BN / WN;
  constexpr int FM = WROWS / 16;
  constexpr int FN = WCOLS / 16;
  constexpr int AH = (NPH == 4) ? FM / 2 : FM;   // A-frags per phase
  constexpr int PA = 256 * 32;   // u16 per A piece
  constexpr int PB = BN * 32;
  constexpr int ABOFF = 4 * PA;
  constexpr int JA = 2;          // stage instr/thread per A piece
  constexpr int JB = BN / 128;
  constexpr int VMS = (NPH == 4) ? (2 * JA + JB) : (JA + JB);  // 6 / 3
  constexpr int VMP = (NPH == 4) ? 8 : 6;   // prologue: certify piece(0,0)
  constexpr int NTOT = NTN * BN;
  constexpr int NTM = 32;        // 8192/256

  __shared__ __align__(16) u16 lds[ABOFF + 4 * PB];

  const int tid = threadIdx.x;
  const int lane = tid & 63;
  const int wave = tid >> 6;
  const int wm = wave / WN;
  const int wn = wave % WN;

  // bijective XCD swizzle (NWG%8==0) + 4x4 supertile decode
  constexpr int NWG = NTM * NTN;
  const int wg = ((int)blockIdx.x & 7) * (NWG / 8) + ((int)blockIdx.x >> 3);
  constexpr int NSN = NTN / 4;
  const int sup = wg >> 4, win = wg & 15;
  const int mt = (sup / NSN) * 4 + (win >> 2);
  const int nt_ = (sup % NSN) * 4 + (win & 3);

  const int e = mt >> 2;  // CAP/256 = 4 m-tiles per expert
  const u16* Ae = Ag + (size_t)mt * 256 * K;
  const u16* Be = Bg + (size_t)e * NTOT * K + (size_t)nt_ * BN * K;

  // ---- hoisted stage addressing (LDS dest linear; src k-slot pre-swizzled) ----
  const int srow = lane >> 2;
  const int kswz = (((lane & 3) ^ ((lane >> 3) & 3)) << 3);
  const u16* srcA[JA];
  int dstA[JA];
  const u16* srcB[JB];
  int dstB[JB];
#pragma unroll
  for (int j = 0; j < JA; ++j) {
    const int cr = (JA * wave + j) * 16 + srow;
    srcA[j] = Ae + (size_t)cr * K + kswz;
    dstA[j] = (JA * wave + j) * 512;
  }
#pragma unroll
  for (int j = 0; j < JB; ++j) {
    const int cr = (JB * wave + j) * 16 + srow;
    srcB[j] = Be + (size_t)cr * K + kswz;
    dstB[j] = (JB * wave + j) * 512;
  }

  auto stageA = [&](int t, int kh) {
    const int pc = (t & 1) * 2 + kh;
    const int koff = t * 64 + kh * 32;
#pragma unroll
    for (int j = 0; j < JA; ++j)
      async_copy16(srcA[j] + koff, &lds[pc * PA + dstA[j]]);
  };
  auto stageB = [&](int t, int kh) {
    const int pc = (t & 1) * 2 + kh;
    const int koff = t * 64 + kh * 32;
#pragma unroll
    for (int j = 0; j < JB; ++j)
      async_copy16(srcB[j] + koff, &lds[ABOFF + pc * PB + dstB[j]]);
  };

  // ---- hoisted frag-read addressing (zero-conflict layout, r2-verified) ----
  const int frow = lane & 15;
  const int fslot = (((lane >> 4) ^ ((lane >> 1) & 3)) << 3);
  const int aoff = (wm * WROWS + frow) * 32 + fslot;   // + frag*512
  const int boff = (wn * WCOLS + frow) * 32 + fslot;

  f32x4 acc[FM][FN] = {};
  bf16x8 af[AH], bf[FN];   // single buffers: reads consumed same phase

  auto rdB = [&](int pc) {
    const u16* pb = &lds[ABOFF + pc * PB + boff];
#pragma unroll
    for (int j = 0; j < FN; ++j) bf[j] = *(const bf16x8*)(pb + j * 512);
  };
  auto rdA = [&](int pc, auto MH) {
    const u16* pa = &lds[pc * PA + aoff];
#pragma unroll
    for (int i = 0; i < AH; ++i)
      af[i] = *(const bf16x8*)(pa + (MH.v * AH + i) * 512);
  };
  auto mfmaC = [&](auto MH) {
    __builtin_amdgcn_s_setprio(1);
#pragma unroll
    for (int i = 0; i < AH; ++i)
#pragma unroll
      for (int j = 0; j < FN; ++j)
        acc[MH.v * AH + i][j] = __builtin_amdgcn_mfma_f32_16x16x32_bf16(
            af[i], bf[j], acc[MH.v * AH + i][j], 0, 0, 0);
    __builtin_amdgcn_s_setprio(0);
  };

  // prologue: stage t0(kh0,kh1)+t1(kh0); certify piece(0,0); enter loop.
  stageA(0, 0); stageB(0, 0);
  stageA(0, 1); stageB(0, 1);
  stageA(1, 0); stageB(1, 0);
  vm_wait<VMP>();
  wgbar();

  for (int t = 0; t < NT; ++t) {
    const int p0 = (t & 1) * 2, p1 = p0 + 1;
    const bool tailVM = (t >= NT - 3);
    if constexpr (NPH == 4) {
      // q0: read p0/mh0; stage A(t+1,1); MFMA p0/mh0
      rdB(p0); rdA(p0, IC<0>{});
      if (t < NT - 1) stageA(t + 1, 1);
      wgbar();
      mfmaC(IC<0>{});
      wgbar();
      // q1: read p0/mh1; stage B(t+1,1); MFMA p0/mh1; vmcnt
      rdA(p0, IC<1>{});
      if (t < NT - 1) stageB(t + 1, 1);
      wgbar();
      mfmaC(IC<1>{});
      if (tailVM) vm_wait<0>(); else vm_wait<VMS>();
      wgbar();
      // q2: read p1/mh0; stage A(t+2,0); MFMA p1/mh0
      rdB(p1); rdA(p1, IC<0>{});
      if (t < NT - 2) stageA(t + 2, 0);
      wgbar();
      mfmaC(IC<0>{});
      wgbar();
      // q3: read p1/mh1; stage B(t+2,0); MFMA p1/mh1; vmcnt
      rdA(p1, IC<1>{});
      if (t < NT - 2) stageB(t + 2, 0);
      wgbar();
      mfmaC(IC<1>{});
      if (tailVM) vm_wait<0>(); else vm_wait<VMS>();
      wgbar();
    } else {
      // q0: read p0; stage A,B(t+1,1); MFMA; vmcnt
      rdB(p0); rdA(p0, IC<0>{});
      if (t < NT - 1) { stageA(t + 1, 1); stageB(t + 1, 1); }
      wgbar();
      mfmaC(IC<0>{});
      if (tailVM) vm_wait<0>(); else vm_wait<VMS>();
      wgbar();
      // q1: read p1; stage A,B(t+2,0); MFMA; vmcnt
      rdB(p1); rdA(p1, IC<0>{});
      if (t < NT - 2) { stageA(t + 2, 0); stageB(t + 2, 0); }
      wgbar();
      mfmaC(IC<0>{});
      if (tailVM) vm_wait<0>(); else vm_wait<VMS>();
      wgbar();
    }
  }

  // epilogue: C/D layout col=lane&15, row=(lane>>4)*4+reg
  const int lr = (lane >> 4) * 4;
  const int lc = lane & 15;
  const size_t Crow0 = (size_t)mt * 256 + wm * WROWS;
  const int Ccol0 = nt_ * BN + wn * WCOLS;
#pragma unroll
  for (int fm = 0; fm < FM; ++fm)
#pragma unroll
    for (int fn = 0; fn < FN; ++fn) {
      const int col = Ccol0 + fn * 16 + lc;
#pragma unroll
      for (int r = 0; r < 4; ++r) {
        const size_t row = Crow0 + fm * 16 + lr + r;
        if constexpr (GELU) {
          ((u16*)Cg)[row * NTOT + col] = f2bf(gelu_tanh(acc[fm][fn][r]));
        } else {
          ((float*)Cg)[row * NTOT + col] = acc[fm][fn][r];
        }
      }
    }
}

extern "C" void kernel_launch(void* const* d_in, const int* in_sizes, int n_in,
                              void* d_out, int out_size, void* d_ws, size_t ws_size,
                              hipStream_t stream) {
  const float* x = (const float*)d_in[0];
  const float* w1 = (const float*)d_in[1];
  const float* w2 = (const float*)d_in[2];

  u16* ws_x = (u16*)d_ws;                               // [T][H] bf16
  u16* ws_w1 = ws_x + (size_t)T_TOK * H_DIM;            // [E][F][H] bf16
  u16* ws_w2t = ws_w1 + (size_t)E_NUM * F_DIM * H_DIM;  // [E][H][F] bf16
  u16* ws_h = ws_w2t + (size_t)E_NUM * H_DIM * F_DIM;   // [T][F] bf16
  const size_t need =
      ((size_t)T_TOK * H_DIM + 2 * (size_t)E_NUM * F_DIM * H_DIM + (size_t)T_TOK * F_DIM) * 2;
  if (ws_size < need) return;

  k_convert<<<1024, 256, 0, stream>>>(x, ws_x, (long)T_TOK * H_DIM);
  k_convert<<<2048, 256, 0, stream>>>(w1, ws_w1, (long)E_NUM * F_DIM * H_DIM);
  k_transpose_w2<<<E_NUM * (F_DIM / 32) * (H_DIM / 32), 256, 0, stream>>>(w2, ws_w2t);

  // GEMM1: h = gelu(x_e @ w1_e^T) -> [T][F] bf16
  //   tile 256x256, waves 2x4, 4-phase, NTN=16, NT=16 -> 512 blocks
  k_gemm<256, 2, 4, 16, 16, true, 4><<<512, 512, 0, stream>>>(ws_x, ws_w1, ws_h);
  // GEMM2: out = h_e @ w2t_e^T -> [T][H] f32
  //   tile 256x128, waves 4x2, 2-phase, NTN=8, NT=64 -> 256 blocks
  k_gemm<128, 4, 2, 8, 64, false, 2><<<256, 512, 0, stream>>>(ws_h, ws_w2t, d_out);
}